// Round 7
// baseline (260.151 us; speedup 1.0000x reference)
//
#include <hip/hip_runtime.h>
#include <math.h>

#define BB 4
#define CC 256
#define NN 4096
#define DQ 32
#define LOG2E 1.44269504f

typedef _Float16 half8 __attribute__((ext_vector_type(8)));
typedef _Float16 half4 __attribute__((ext_vector_type(4)));
typedef float float4v __attribute__((ext_vector_type(4)));

// ---------------- prep: W -> f16 (log2e folded into Wq/bq) ----------------
__global__ __launch_bounds__(64) void prep_kernel(
    const float* __restrict__ Wq, const float* __restrict__ bq,
    const float* __restrict__ Wk, const float* __restrict__ bk,
    const float* __restrict__ Wv, const float* __restrict__ bv,
    _Float16* __restrict__ Wh, float* __restrict__ bh)
{
    int o = blockIdx.x, t = threadIdx.x;
    const float* src; float scale = 1.0f, bias;
    if (o < DQ)            { src = Wq + o * CC;        scale = LOG2E; bias = bq[o] * LOG2E; }
    else if (o < 2 * DQ)   { src = Wk + (o - DQ) * CC;                bias = bk[o - DQ]; }
    else                   { src = Wv + (o - 2 * DQ) * CC;            bias = bv[o - 2 * DQ]; }
    float4 v = *(const float4*)(src + t * 4);
    half4 h = { (_Float16)(v.x * scale), (_Float16)(v.y * scale),
                (_Float16)(v.z * scale), (_Float16)(v.w * scale) };
    *(half4*)(Wh + o * CC + t * 4) = h;
    if (t == 0) bh[o] = bias;
}

// ---------------- proj: MFMA GEMM, 320 outputs x 16-pixel tile ----------------
// grid 1024 (4 blocks/CU). Qt/Kt: [b][n][32] f16. Vh: [b][c][n] f16.
__global__ __launch_bounds__(256) void proj_kernel(
    const float* __restrict__ x, const _Float16* __restrict__ Wh,
    const float* __restrict__ bh,
    _Float16* __restrict__ Qt, _Float16* __restrict__ Kt,
    _Float16* __restrict__ Vh)
{
    __shared__ _Float16 xl[16 * 256];     // [n][c], chunk-of-8 swizzle: chunk' = (c>>3) ^ n
    __shared__ _Float16 os_qk[16 * 72];   // [n][o<64 + pad]
    __shared__ _Float16 os_v[256 * 24];   // [c][n + pad]

    const int tid = threadIdx.x;
    const int lane = tid & 63, w = tid >> 6;
    const int i16 = lane & 15, q = lane >> 4;
    const int n0 = blockIdx.x * 16, b = blockIdx.y;

    // stage x tile -> f16 [n][c] via 4x4 in-register transpose
    const float* xb = x + (size_t)b * CC * NN + n0;
    {
        int c0 = 4 * (tid >> 2);
        int nn = 4 * (tid & 3);
        float4 rr[4];
        #pragma unroll
        for (int j = 0; j < 4; ++j)
            rr[j] = *(const float4*)(xb + (size_t)(c0 + j) * NN + nn);
        #pragma unroll
        for (int e = 0; e < 4; ++e) {
            int n = nn + e;
            half4 h = { (_Float16)((const float*)&rr[0])[e],
                        (_Float16)((const float*)&rr[1])[e],
                        (_Float16)((const float*)&rr[2])[e],
                        (_Float16)((const float*)&rr[3])[e] };
            int chunk = (c0 >> 3) ^ n;
            *(half4*)&xl[n * 256 + chunk * 8 + (c0 & 7)] = h;
        }
    }

    float4v acc[5];
    const int obase = 80 * w;
    #pragma unroll
    for (int ot = 0; ot < 5; ++ot) {
        float4 b4 = *(const float4*)(bh + obase + 16 * ot + 4 * q);
        acc[ot] = (float4v){b4.x, b4.y, b4.z, b4.w};
    }

    const _Float16* wbase = Wh + (size_t)(obase + i16) * CC + 8 * q;
    half8 afc[5];
    #pragma unroll
    for (int ot = 0; ot < 5; ++ot)
        afc[ot] = *(const half8*)(wbase + (size_t)16 * ot * CC);
    __syncthreads();

    #pragma unroll
    for (int k = 0; k < 8; ++k) {
        half8 afn[5];
        int kn = (k + 1) & 7;
        #pragma unroll
        for (int ot = 0; ot < 5; ++ot)
            afn[ot] = *(const half8*)(wbase + (size_t)16 * ot * CC + kn * 32);
        half8 bf = *(const half8*)&xl[i16 * 256 + (((4 * k + q) ^ i16) * 8)];
        #pragma unroll
        for (int ot = 0; ot < 5; ++ot)
            acc[ot] = __builtin_amdgcn_mfma_f32_16x16x32_f16(afc[ot], bf, acc[ot], 0, 0, 0);
        #pragma unroll
        for (int ot = 0; ot < 5; ++ot)
            afc[ot] = afn[ot];
    }

    #pragma unroll
    for (int ot = 0; ot < 5; ++ot) {
        int og = obase + 16 * ot;
        if (og < 64) {
            half4 hv = { (_Float16)acc[ot][0], (_Float16)acc[ot][1],
                         (_Float16)acc[ot][2], (_Float16)acc[ot][3] };
            *(half4*)&os_qk[i16 * 72 + og + 4 * q] = hv;
        } else {
            int cb = og - 64 + 4 * q;
            #pragma unroll
            for (int r = 0; r < 4; ++r)
                os_v[(cb + r) * 24 + i16] = (_Float16)acc[ot][r];
        }
    }
    __syncthreads();

    _Float16* Qtb = Qt + (size_t)b * NN * DQ;
    _Float16* Ktb = Kt + (size_t)b * NN * DQ;
    if (tid < 128) {
        int n = tid >> 3, p = tid & 7;
        half8 hv = *(const half8*)&os_qk[n * 72 + 8 * p];
        if (p < 4) *(half8*)(Qtb + (size_t)(n0 + n) * DQ + 8 * p) = hv;
        else       *(half8*)(Ktb + (size_t)(n0 + n) * DQ + 8 * (p - 4)) = hv;
    }
    _Float16* Vb = Vh + (size_t)b * CC * NN;
    #pragma unroll
    for (int u = 0; u < 2; ++u) {
        int c = u * 128 + (tid >> 1), p = tid & 1;
        half8 hv = *(const half8*)&os_v[c * 24 + 8 * p];
        *(half8*)(Vb + (size_t)c * NN + n0 + 8 * p) = hv;
    }
}

// ---------------- rowstat: l[q] = sum_j exp2(S[q][j]) over a key quarter ----
#define RS_TILE(KC, KN, U)                                                     \
    {                                                                          \
        const int un = ((U) + 1) & 15;                                         \
        _Pragma("unroll")                                                      \
        for (int jt = 0; jt < 4; ++jt)                                         \
            KN[jt] = *(const half8*)(kb0 + un * 64 * DQ + jt * 16 * DQ);       \
        _Pragma("unroll")                                                      \
        for (int jt = 0; jt < 4; ++jt) {                                       \
            float4v z = {0.f, 0.f, 0.f, 0.f};                                  \
            float4v s = __builtin_amdgcn_mfma_f32_16x16x32_f16(KC[jt], qb, z, 0, 0, 0); \
            l += exp2f(s[0]); l += exp2f(s[1]);                                \
            l += exp2f(s[2]); l += exp2f(s[3]);                                \
        }                                                                      \
    }

__global__ __launch_bounds__(256) void rowstat_kernel(
    const _Float16* __restrict__ Qt, const _Float16* __restrict__ Kt,
    float* __restrict__ L)
{
    const int tid = threadIdx.x;
    const int lane = tid & 63, w = tid >> 6;
    const int i16 = lane & 15, q = lane >> 4;
    const int q0 = blockIdx.x * 64, js = blockIdx.y, b = blockIdx.z;

    const _Float16* Qtb = Qt + (size_t)b * NN * DQ;
    const _Float16* Ktb = Kt + (size_t)b * NN * DQ;
    half8 qb = *(const half8*)(Qtb + (size_t)(q0 + 16 * w + i16) * DQ + 8 * q);
    const _Float16* kb0 = Ktb + (size_t)(js * 1024 + i16) * DQ + 8 * q;

    float l = 0.f;
    half8 kA[4], kB[4];
    #pragma unroll
    for (int jt = 0; jt < 4; ++jt)
        kA[jt] = *(const half8*)(kb0 + jt * 16 * DQ);
    for (int uu = 0; uu < 8; ++uu) {
        RS_TILE(kA, kB, 2 * uu);
        RS_TILE(kB, kA, 2 * uu + 1);
    }
    l += __shfl_xor(l, 16, 64);
    l += __shfl_xor(l, 32, 64);
    if (q == 0)
        L[((size_t)b * 4 + js) * NN + q0 + 16 * w + i16] = l;
}

// ---------------- attn: S once/block, P via LDS as A-frag, V direct-global B-frag ----
// Block: 512 thr = 8 waves. Tile: 64 queries x 256 channels x 2048 keys (ks half).
// Wave w: S-tile (it=w&3, jt=w>>2) of each 32-key tile; PV channels [32w,32w+32).
// pl[i][j] double-buffered; ONE lgkm-only barrier per tile. ks=0 writes f32 to out,
// ks=1 writes f16 partial to Ph; reduce_kernel fuses out+x+Ph.
__global__ __launch_bounds__(512) void attn_kernel(
    const _Float16* __restrict__ Qt, const _Float16* __restrict__ Kt,
    const _Float16* __restrict__ Vh, const float* __restrict__ L,
    float* __restrict__ out, _Float16* __restrict__ Ph)
{
    __shared__ _Float16 pl[2][64 * 36];   // [i][j + pad4]

    const int tid = threadIdx.x;
    const int w = tid >> 6, lane = tid & 63;
    const int i16 = lane & 15, q = lane >> 4;
    const int itw = w & 3, jtw = w >> 2;
    // id&7 -> (b,ks): consecutive ids land on different XCDs; each XCD sees one (b,ks)
    const int id = blockIdx.x;
    const int b = (id & 7) >> 1;
    const int ks = id & 1;
    const int i0 = 64 * (id >> 3);
    const int j00 = ks * 2048;

    // combined log2(l) for this wave's S rows: i = i0 + 16*itw + 4q + r
    float4v lgs;
    {
        float4v s = {0.f, 0.f, 0.f, 0.f};
        #pragma unroll
        for (int js = 0; js < 4; ++js)
            s += *(const float4v*)(L + ((size_t)b * 4 + js) * NN + i0 + 16 * itw + 4 * q);
        lgs[0] = log2f(s[0]); lgs[1] = log2f(s[1]);
        lgs[2] = log2f(s[2]); lgs[3] = log2f(s[3]);
    }

    // persistent Q A-frag for this wave's S-tile
    half8 qf = *(const half8*)(Qt + (size_t)b * NN * DQ
                               + (size_t)(i0 + 16 * itw + i16) * DQ + 8 * q);

    const _Float16* kptr = Kt + (size_t)b * NN * DQ
                         + (size_t)(j00 + 16 * jtw + i16) * DQ + 8 * q;
    const _Float16* vptr0 = Vh + (size_t)b * CC * NN
                          + (size_t)(32 * w + i16) * NN + j00 + 8 * q;
    const _Float16* vptr1 = vptr0 + (size_t)16 * NN;

    float4v O[4][2];
    #pragma unroll
    for (int it = 0; it < 4; ++it)
        #pragma unroll
        for (int ct = 0; ct < 2; ++ct)
            O[it][ct] = (float4v){0.f, 0.f, 0.f, 0.f};

    half8 kc, kn, vc0, vc1, vn0, vn1;
    kc  = *(const half8*)kptr;
    vc0 = *(const half8*)vptr0;
    vc1 = *(const half8*)vptr1;

    const int jcol = 16 * jtw + i16;

    for (int t = 0; t < 64; ++t) {
        if (t < 63) {   // prefetch next tile's frags (global, in-flight across barrier)
            kn  = *(const half8*)(kptr + (size_t)(t + 1) * 32 * DQ);
            vn0 = *(const half8*)(vptr0 + (t + 1) * 32);
            vn1 = *(const half8*)(vptr1 + (t + 1) * 32);
        }
        _Float16* plb = &pl[t & 1][0];

        // S tile: D[i=16itw+4q+r][j=16jtw+i16]
        {
            float4v z = {0.f, 0.f, 0.f, 0.f};
            float4v s = __builtin_amdgcn_mfma_f32_16x16x32_f16(qf, kc, z, 0, 0, 0);
            #pragma unroll
            for (int r = 0; r < 4; ++r)
                plb[(16 * itw + 4 * q + r) * 36 + jcol] = (_Float16)exp2f(s[r] - lgs[r]);
        }
        // lgkm-only barrier: keeps global prefetches in flight (no vmcnt drain)
        asm volatile("s_waitcnt lgkmcnt(0)\n\ts_barrier" ::: "memory");

        // P A-frags (all 4 query sub-tiles) + PV
        half8 pa[4];
        #pragma unroll
        for (int it = 0; it < 4; ++it)
            pa[it] = *(const half8*)&plb[(16 * it + i16) * 36 + 8 * q];
        #pragma unroll
        for (int it = 0; it < 4; ++it) {
            O[it][0] = __builtin_amdgcn_mfma_f32_16x16x32_f16(pa[it], vc0, O[it][0], 0, 0, 0);
            O[it][1] = __builtin_amdgcn_mfma_f32_16x16x32_f16(pa[it], vc1, O[it][1], 0, 0, 0);
        }
        kc = kn; vc0 = vn0; vc1 = vn1;
    }

    // epilogue: lane holds O[i=16it+4q+r][c=32w+16ct+i16]
    if (ks == 0) {
        float* ob = out + (size_t)b * CC * NN;
        #pragma unroll
        for (int it = 0; it < 4; ++it)
            #pragma unroll
            for (int ct = 0; ct < 2; ++ct) {
                int c = 32 * w + 16 * ct + i16;
                *(float4v*)(ob + (size_t)c * NN + i0 + 16 * it + 4 * q) = O[it][ct];
            }
    } else {
        _Float16* pb = Ph + (size_t)b * CC * NN;
        #pragma unroll
        for (int it = 0; it < 4; ++it)
            #pragma unroll
            for (int ct = 0; ct < 2; ++ct) {
                int c = 32 * w + 16 * ct + i16;
                half4 hv = { (_Float16)O[it][ct][0], (_Float16)O[it][ct][1],
                             (_Float16)O[it][ct][2], (_Float16)O[it][ct][3] };
                *(half4*)(pb + (size_t)c * NN + i0 + 16 * it + 4 * q) = hv;
            }
    }
}

// ---------------- reduce: out = out(ks0 partial) + x + Ph(ks1 partial) ----------------
__global__ __launch_bounds__(256) void reduce_kernel(
    const float* __restrict__ x, const _Float16* __restrict__ Ph,
    float* __restrict__ out)
{
    size_t i8 = ((size_t)blockIdx.x * 256 + threadIdx.x) * 8;
    float4 o0 = *(const float4*)(out + i8);
    float4 o1 = *(const float4*)(out + i8 + 4);
    float4 x0 = *(const float4*)(x + i8);
    float4 x1 = *(const float4*)(x + i8 + 4);
    half8 p = *(const half8*)(Ph + i8);
    float4 r0 = { o0.x + x0.x + (float)p[0], o0.y + x0.y + (float)p[1],
                  o0.z + x0.z + (float)p[2], o0.w + x0.w + (float)p[3] };
    float4 r1 = { o1.x + x1.x + (float)p[4], o1.y + x1.y + (float)p[5],
                  o1.z + x1.z + (float)p[6], o1.w + x1.w + (float)p[7] };
    *(float4*)(out + i8) = r0;
    *(float4*)(out + i8 + 4) = r1;
}

extern "C" void kernel_launch(void* const* d_in, const int* in_sizes, int n_in,
                              void* d_out, int out_size, void* d_ws, size_t ws_size,
                              hipStream_t stream) {
    const float* x  = (const float*)d_in[0];
    const float* Wq = (const float*)d_in[1];
    const float* bq = (const float*)d_in[2];
    const float* Wk = (const float*)d_in[3];
    const float* bk = (const float*)d_in[4];
    const float* Wv = (const float*)d_in[5];
    const float* bv = (const float*)d_in[6];
    float* out = (float*)d_out;

    char* ws = (char*)d_ws;
    _Float16* Wh = (_Float16*)(ws);                 // 320*256*2 = 163840
    float*    bh = (float*)(ws + 163840);           // 1280
    _Float16* Qt = (_Float16*)(ws + 262144);        // 1 MB
    _Float16* Kt = (_Float16*)(ws + 1310720);       // 1 MB
    _Float16* Vh = (_Float16*)(ws + 2359296);       // 8 MB
    float*    L  = (float*)(ws + 10747904);         // 4*4*4096*4 = 256 KB
    _Float16* Ph = (_Float16*)(ws + 11010048);      // 4*256*4096*2 = 8 MB

    prep_kernel<<<dim3(320), 64, 0, stream>>>(Wq, bq, Wk, bk, Wv, bv, Wh, bh);
    proj_kernel<<<dim3(NN / 16, BB), 256, 0, stream>>>(x, Wh, bh, Qt, Kt, Vh);
    rowstat_kernel<<<dim3(NN / 64, 4, BB), 256, 0, stream>>>(Qt, Kt, L);
    attn_kernel<<<dim3(512), 512, 0, stream>>>(Qt, Kt, Vh, L, out, Ph);
    reduce_kernel<<<dim3((BB * CC * NN) / (256 * 8)), 256, 0, stream>>>(x, Ph, out);
}